// Round 1
// baseline (522.334 us; speedup 1.0000x reference)
//
#include <hip/hip_runtime.h>
#include <hip/hip_bf16.h>

#define NTOK 65536   // B*S = 64*1024
#define CIN  768
#define NDIM 8
#define NLVL 15
#define NSLOT 8      // KDE atomic slot arrays (contention spread)

// ---------------------------------------------------------------------------
// Kernel A: zc = z @ Wc^T + bc (f64 accum, fp32 weights in VGPRs, cvt per use),
// stash zc (f64 bits) into first 64B of each out row, accumulate KDE sums
// via collapse-transpose wave reduction + slotted f64 atomics.
// Round-3 changes:
//  - token-PAIR inner loop: each weight f64-convert feeds FMAs of 2 tokens
//    (96 -> 48 cvt/token) and the two shuffle-collapse chains interleave.
//  - KDE exp in f32 (__expf of f32-rounded zc): weights only need ~1e-4 rel,
//    f64 exp (~150 cyc each, 16/lane) was pure VALU waste. zc stays f64
//    (argmin boundary flips at fp32 zc error would exceed tolerance).
//  - per-lane KDE accumulators f32, one cvt to f64 at the block reduce.
// launch_bounds(256,2): ~225 VGPRs must not spill (round-2 lesson:
// (256,3) capped VGPRs -> 200MB spill write + 550MB spill fetch).
// ---------------------------------------------------------------------------
__global__ __launch_bounds__(256, 2)
void fsq_compress_kde(const float* __restrict__ z, const float* __restrict__ Wc,
                      const float* __restrict__ bc, const float* __restrict__ centers,
                      float* out, double* __restrict__ kde_slots)
{
    const int lane  = threadIdx.x & 63;
    const int gwave = blockIdx.x * 4 + (threadIdx.x >> 6);   // 0..8191
    const int base  = gwave * 8;

    // Wc in fp32 regs: Wcf[d][m*4+k] for channel c = 4*lane + 256*m + k
    float Wcf[NDIM][12];
#pragma unroll
    for (int d = 0; d < NDIM; ++d) {
#pragma unroll
        for (int m = 0; m < 3; ++m) {
            const float4 w4 = *(const float4*)(Wc + d * CIN + m * 256 + lane * 4);
            Wcf[d][m * 4 + 0] = w4.x;
            Wcf[d][m * 4 + 1] = w4.y;
            Wcf[d][m * 4 + 2] = w4.z;
            Wcf[d][m * 4 + 3] = w4.w;
        }
    }

    const int    dsel = lane & 7;     // this lane's dim after collapse
    const int    lsel = lane >> 3;    // this lane's KDE level (and stash token)
    const double bsel = (double)bc[dsel];
    const bool   hasB = (lsel < 7);
    const float  cA   = centers[dsel * NLVL + lsel];
    const float  cB   = hasB ? centers[dsel * NLVL + lsel + 8] : 0.0f;

    const int b0 = lane & 1, b1 = lane & 2, b2 = lane & 4;

    float  kA = 0.0f, kB = 0.0f;
    double zst = 0.0;

    // prefetch token pair 0 (tokens 0 and 1): 6 x float4 per lane
    const float* zp = z + (size_t)base * CIN;
    float4 a0 = *(const float4*)(zp +         lane * 4);
    float4 a1 = *(const float4*)(zp +  256 +  lane * 4);
    float4 a2 = *(const float4*)(zp +  512 +  lane * 4);
    float4 a3 = *(const float4*)(zp +  768 +  lane * 4);
    float4 a4 = *(const float4*)(zp + 1024 +  lane * 4);
    float4 a5 = *(const float4*)(zp + 1280 +  lane * 4);

#pragma unroll 1
    for (int tp = 0; tp < 4; ++tp) {
        // prefetch next pair (tp=3 reloads itself: L2-hit, branchless)
        const int    tn  = tp < 3 ? tp + 1 : 3;
        const float* zpn = z + (size_t)(base + 2 * tn) * CIN;
        const float4 n0  = *(const float4*)(zpn +         lane * 4);
        const float4 n1  = *(const float4*)(zpn +  256 +  lane * 4);
        const float4 n2  = *(const float4*)(zpn +  512 +  lane * 4);
        const float4 n3  = *(const float4*)(zpn +  768 +  lane * 4);
        const float4 n4  = *(const float4*)(zpn + 1024 +  lane * 4);
        const float4 n5  = *(const float4*)(zpn + 1280 +  lane * 4);

        double acc0[NDIM], acc1[NDIM];
#pragma unroll
        for (int d = 0; d < NDIM; ++d) { acc0[d] = 0.0; acc1[d] = 0.0; }

        // one weight cvt serves both tokens of the pair
#define CHUNK(AV, BV, W0)                                                     \
        {                                                                     \
            const double x0a = (double)AV.x, x1a = (double)AV.y;              \
            const double x2a = (double)AV.z, x3a = (double)AV.w;              \
            const double x0b = (double)BV.x, x1b = (double)BV.y;              \
            const double x2b = (double)BV.z, x3b = (double)BV.w;              \
            _Pragma("unroll")                                                 \
            for (int d = 0; d < NDIM; ++d) {                                  \
                const double w0 = (double)Wcf[d][(W0) + 0];                   \
                const double w1 = (double)Wcf[d][(W0) + 1];                   \
                const double w2 = (double)Wcf[d][(W0) + 2];                   \
                const double w3 = (double)Wcf[d][(W0) + 3];                   \
                acc0[d] = fma(x0a, w0, acc0[d]);                              \
                acc0[d] = fma(x1a, w1, acc0[d]);                              \
                acc0[d] = fma(x2a, w2, acc0[d]);                              \
                acc0[d] = fma(x3a, w3, acc0[d]);                              \
                acc1[d] = fma(x0b, w0, acc1[d]);                              \
                acc1[d] = fma(x1b, w1, acc1[d]);                              \
                acc1[d] = fma(x2b, w2, acc1[d]);                              \
                acc1[d] = fma(x3b, w3, acc1[d]);                              \
            }                                                                 \
        }
        CHUNK(a0, a3, 0)
        CHUNK(a1, a4, 4)
        CHUNK(a2, a5, 8)
#undef CHUNK

        // collapse-transpose both tokens, interleaved (independent chains)
        double r0[4], r1[4];
#pragma unroll
        for (int j = 0; j < 4; ++j) {
            const double snd0 = b0 ? acc0[2 * j] : acc0[2 * j + 1];
            const double kp0  = b0 ? acc0[2 * j + 1] : acc0[2 * j];
            r0[j] = kp0 + __shfl_xor(snd0, 1, 64);
            const double snd1 = b0 ? acc1[2 * j] : acc1[2 * j + 1];
            const double kp1  = b0 ? acc1[2 * j + 1] : acc1[2 * j];
            r1[j] = kp1 + __shfl_xor(snd1, 1, 64);
        }
        double q0[2], q1[2];
#pragma unroll
        for (int i = 0; i < 2; ++i) {
            const double snd0 = b1 ? r0[2 * i] : r0[2 * i + 1];
            const double kp0  = b1 ? r0[2 * i + 1] : r0[2 * i];
            q0[i] = kp0 + __shfl_xor(snd0, 2, 64);
            const double snd1 = b1 ? r1[2 * i] : r1[2 * i + 1];
            const double kp1  = b1 ? r1[2 * i + 1] : r1[2 * i];
            q1[i] = kp1 + __shfl_xor(snd1, 2, 64);
        }
        double s0, s1;
        {
            const double snd0 = b2 ? q0[0] : q0[1];
            const double kp0  = b2 ? q0[1] : q0[0];
            s0 = kp0 + __shfl_xor(snd0, 4, 64);
            const double snd1 = b2 ? q1[0] : q1[1];
            const double kp1  = b2 ? q1[1] : q1[0];
            s1 = kp1 + __shfl_xor(snd1, 4, 64);
            s0 += __shfl_xor(s0, 8, 64);   s1 += __shfl_xor(s1, 8, 64);
            s0 += __shfl_xor(s0, 16, 64);  s1 += __shfl_xor(s1, 16, 64);
            s0 += __shfl_xor(s0, 32, 64);  s1 += __shfl_xor(s1, 32, 64);
            s0 += bsel;                    s1 += bsel;
        }

        if (2 * tp     == lsel) zst = s0;   // keep for coalesced stash
        if (2 * tp + 1 == lsel) zst = s1;

        // KDE in f32: exp(-0.5*((c-s)/0.5)^2) = exp(-2*(c-s)^2)
        const float sf0 = (float)s0, sf1 = (float)s1;
        {
            const float dA0 = cA - sf0;
            const float dA1 = cA - sf1;
            kA += __expf(dA0 * dA0 * -2.0f);
            kA += __expf(dA1 * dA1 * -2.0f);
            const float dB0 = cB - sf0;
            const float dB1 = cB - sf1;
            const float eB  = __expf(dB0 * dB0 * -2.0f) +
                              __expf(dB1 * dB1 * -2.0f);
            if (hasB) kB += eB;
        }

        a0 = n0; a1 = n1; a2 = n2; a3 = n3; a4 = n4; a5 = n5;
    }

    // stash zc: lane -> token base+lsel, dim dsel (64B per row head)
    __builtin_memcpy(out + (size_t)(base + lsel) * CIN + 2 * dsel, &zst, 8);

    // block reduce (4 waves, identical lane mapping) in f32, slotted f64 atomics
    __shared__ float sAl[256];
    __shared__ float sBl[256];
    sAl[threadIdx.x] = kA;
    sBl[threadIdx.x] = kB;
    __syncthreads();
    if (threadIdx.x < 64) {
        const float rA = sAl[threadIdx.x] + sAl[threadIdx.x + 64] +
                         sAl[threadIdx.x + 128] + sAl[threadIdx.x + 192];
        const float rB = sBl[threadIdx.x] + sBl[threadIdx.x + 64] +
                         sBl[threadIdx.x + 128] + sBl[threadIdx.x + 192];
        const int d = threadIdx.x & 7, l = threadIdx.x >> 3;
        double* slot = kde_slots + (blockIdx.x & (NSLOT - 1)) * 128;
        unsafeAtomicAdd(&slot[d * NLVL + l], (double)rA);
        if (l < 7) unsafeAtomicAdd(&slot[d * NLVL + 8 + l], (double)rB);
    }
}

// ---------------------------------------------------------------------------
// Kernel C: recompute scaled centers in LDS (fused scale step), f64 argmin
// per (token, dim), fp32 expand z_q = q @ We^T + be. Reads zc from the row
// heads this wave later overwrites (load-before-store within the wave).
// launch_bounds(256,2): We's 96-reg array must not spill (round-2 lesson).
// ---------------------------------------------------------------------------
__global__ __launch_bounds__(256, 2)
void fsq_quant_expand(const double* __restrict__ kde_slots,
                      const float* __restrict__ centers,
                      const float* __restrict__ We, const float* __restrict__ be,
                      float* out, float* out_scalar)
{
    __shared__ double w_lds[NDIM * NLVL];
    __shared__ double sc_lds[NDIM * NLVL];
    {
        const int t = threadIdx.x;
        if (t < NDIM * NLVL) {
            double a = 0.0;
#pragma unroll
            for (int k = 0; k < NSLOT; ++k) a += kde_slots[k * 128 + t];
            w_lds[t] = a * (1.0 / 65536.0) + 1e-6;
        }
        __syncthreads();
        if (t < NDIM * NLVL) {
            const int d = t / NLVL;
            double s = 0.0;
#pragma unroll
            for (int l = 0; l < NLVL; ++l) s += w_lds[d * NLVL + l];
            sc_lds[t] = (double)centers[t] * (w_lds[t] / s);
        }
        if (blockIdx.x == 0 && t == 0) *out_scalar = 0.0f;
        __syncthreads();
    }

    const int lane  = threadIdx.x & 63;
    const int gwave = blockIdx.x * 4 + (threadIdx.x >> 6);
    const int base  = gwave * 8;

    // We in fp32 regs: channel c = lane*4 + 256*m + k
    float Wer[12][NDIM];
    float ber[12];
#pragma unroll
    for (int m = 0; m < 3; ++m) {
#pragma unroll
        for (int k = 0; k < 4; ++k) {
            const int    c  = lane * 4 + 256 * m + k;
            const float4 u0 = *(const float4*)(We + c * NDIM);
            const float4 u1 = *(const float4*)(We + c * NDIM + 4);
            Wer[m * 4 + k][0] = u0.x; Wer[m * 4 + k][1] = u0.y;
            Wer[m * 4 + k][2] = u0.z; Wer[m * 4 + k][3] = u0.w;
            Wer[m * 4 + k][4] = u1.x; Wer[m * 4 + k][5] = u1.y;
            Wer[m * 4 + k][6] = u1.z; Wer[m * 4 + k][7] = u1.w;
            ber[m * 4 + k] = be[c];
        }
    }

    const int dsel = lane & 7;      // this lane's dim
    const int tsel = lane >> 3;     // this lane's token within the group of 8

    // one zc value per lane: (token base+tsel, dim dsel) — before any store
    double zd;
    __builtin_memcpy(&zd, out + (size_t)(base + tsel) * CIN + 2 * dsel, 8);

    // first-min argmin over the 15 scaled centers of dim dsel (matches np)
    const double* sc = sc_lds + dsel * NLVL;
    double best = fabs(zd - sc[0]);
    double q    = sc[0];
#pragma unroll
    for (int l = 1; l < NLVL; ++l) {
        const double dd = fabs(zd - sc[l]);
        if (dd < best) { best = dd; q = sc[l]; }
    }
    const float qf = (float)q;

#pragma unroll 1
    for (int t = 0; t < 8; ++t) {
        float qa[NDIM];
#pragma unroll
        for (int j = 0; j < NDIM; ++j) qa[j] = __shfl(qf, t * 8 + j, 64);

        float* op = out + (size_t)(base + t) * CIN;
#pragma unroll
        for (int m = 0; m < 3; ++m) {
            float v[4];
#pragma unroll
            for (int k = 0; k < 4; ++k) {
                float s = ber[m * 4 + k];
#pragma unroll
                for (int j = 0; j < NDIM; ++j)
                    s = fmaf(qa[j], Wer[m * 4 + k][j], s);
                v[k] = s;
            }
            *(float4*)(op + m * 256 + lane * 4) = make_float4(v[0], v[1], v[2], v[3]);
        }
    }
}

// ---------------------------------------------------------------------------
extern "C" void kernel_launch(void* const* d_in, const int* in_sizes, int n_in,
                              void* d_out, int out_size, void* d_ws, size_t ws_size,
                              hipStream_t stream)
{
    const float* z       = (const float*)d_in[0];
    const float* Wc      = (const float*)d_in[1];
    const float* bc      = (const float*)d_in[2];
    const float* We      = (const float*)d_in[3];
    const float* be      = (const float*)d_in[4];
    const float* centers = (const float*)d_in[5];
    float*       out     = (float*)d_out;

    double* kde_slots = (double*)d_ws;   // NSLOT x 128 doubles = 8 KB

    hipMemsetAsync(kde_slots, 0, NSLOT * 128 * sizeof(double), stream);
    fsq_compress_kde<<<2048, 256, 0, stream>>>(z, Wc, bc, centers, out, kde_slots);
    fsq_quant_expand<<<2048, 256, 0, stream>>>(kde_slots, centers, We, be, out,
                                               out + (size_t)out_size - 1);
}

// Round 2
// 380.804 us; speedup vs baseline: 1.3717x; 1.3717x over previous
//
#include <hip/hip_runtime.h>
#include <hip/hip_bf16.h>

#define NTOK 65536   // B*S = 64*1024
#define CIN  768
#define NDIM 8
#define NLVL 15
#define NSLOT 8      // KDE atomic slot arrays (contention spread)

// ---------------------------------------------------------------------------
// Kernel A: zc = z @ Wc^T + bc (f64 accum, fp32 weights in VGPRs, cvt per use),
// stash zc (f64 bits) into first 64B of each out row, accumulate KDE sums
// via collapse-transpose wave reduction + slotted f64 atomics.
// 2048 blocks x 4 waves; each wave owns 8 consecutive tokens.
// launch_bounds(256,2): 96-reg weight array MUST NOT spill.
//   round-2 lesson: (256,3) capped VGPRs -> 200MB spill write + 550MB fetch.
//   round-3 lesson: token-PAIR loop (2x acc + 2x prefetch bufs) crossed the
//   same cliff at (256,2) -> VGPR=128, 422MB spill writes, A went 115->231us.
//   Single-token structure is the proven register fit. DO NOT widen it.
// round-3 keeper (validated: absmax identical 2^-11): KDE exp in f32
// (__expf of f32-rounded zc) instead of f64 ocml exp — weights feed w/sum(w)
// which only needs ~1e-6 rel; zc itself stays f64 for the argmin.
// ---------------------------------------------------------------------------
__global__ __launch_bounds__(256, 2)
void fsq_compress_kde(const float* __restrict__ z, const float* __restrict__ Wc,
                      const float* __restrict__ bc, const float* __restrict__ centers,
                      float* out, double* __restrict__ kde_slots)
{
    const int lane  = threadIdx.x & 63;
    const int gwave = blockIdx.x * 4 + (threadIdx.x >> 6);   // 0..8191
    const int base  = gwave * 8;

    // Wc in fp32 regs: Wcf[d][m*4+k] for channel c = 4*lane + 256*m + k
    float Wcf[NDIM][12];
#pragma unroll
    for (int d = 0; d < NDIM; ++d) {
#pragma unroll
        for (int m = 0; m < 3; ++m) {
            const float4 w4 = *(const float4*)(Wc + d * CIN + m * 256 + lane * 4);
            Wcf[d][m * 4 + 0] = w4.x;
            Wcf[d][m * 4 + 1] = w4.y;
            Wcf[d][m * 4 + 2] = w4.z;
            Wcf[d][m * 4 + 3] = w4.w;
        }
    }

    const int    dsel = lane & 7;     // this lane's dim after collapse
    const int    lsel = lane >> 3;    // this lane's KDE level (and stash token)
    const double bsel = (double)bc[dsel];
    const bool   hasB = (lsel < 7);
    const float  cA   = centers[dsel * NLVL + lsel];
    const float  cB   = hasB ? centers[dsel * NLVL + lsel + 8] : 0.0f;

    const int b0 = lane & 1, b1 = lane & 2, b2 = lane & 4;

    float  kA = 0.0f, kB = 0.0f;
    double zst = 0.0;

    // prefetch token 0
    const float* zp = z + (size_t)base * CIN;
    float4 a0 = *(const float4*)(zp + lane * 4);
    float4 a1 = *(const float4*)(zp + 256 + lane * 4);
    float4 a2 = *(const float4*)(zp + 512 + lane * 4);

#pragma unroll 1
    for (int t = 0; t < 8; ++t) {
        // prefetch next token (t=7 reloads itself: L2-hit, branchless)
        const int    tn  = t < 7 ? t + 1 : 7;
        const float* zpn = z + (size_t)(base + tn) * CIN;
        const float4 n0  = *(const float4*)(zpn + lane * 4);
        const float4 n1  = *(const float4*)(zpn + 256 + lane * 4);
        const float4 n2  = *(const float4*)(zpn + 512 + lane * 4);

        double acc[NDIM];
#pragma unroll
        for (int d = 0; d < NDIM; ++d) acc[d] = 0.0;

        {
            const double x0 = (double)a0.x, x1 = (double)a0.y;
            const double x2 = (double)a0.z, x3 = (double)a0.w;
#pragma unroll
            for (int d = 0; d < NDIM; ++d) {
                acc[d] = fma(x0, (double)Wcf[d][0], acc[d]);
                acc[d] = fma(x1, (double)Wcf[d][1], acc[d]);
                acc[d] = fma(x2, (double)Wcf[d][2], acc[d]);
                acc[d] = fma(x3, (double)Wcf[d][3], acc[d]);
            }
        }
        {
            const double x0 = (double)a1.x, x1 = (double)a1.y;
            const double x2 = (double)a1.z, x3 = (double)a1.w;
#pragma unroll
            for (int d = 0; d < NDIM; ++d) {
                acc[d] = fma(x0, (double)Wcf[d][4], acc[d]);
                acc[d] = fma(x1, (double)Wcf[d][5], acc[d]);
                acc[d] = fma(x2, (double)Wcf[d][6], acc[d]);
                acc[d] = fma(x3, (double)Wcf[d][7], acc[d]);
            }
        }
        {
            const double x0 = (double)a2.x, x1 = (double)a2.y;
            const double x2 = (double)a2.z, x3 = (double)a2.w;
#pragma unroll
            for (int d = 0; d < NDIM; ++d) {
                acc[d] = fma(x0, (double)Wcf[d][8],  acc[d]);
                acc[d] = fma(x1, (double)Wcf[d][9],  acc[d]);
                acc[d] = fma(x2, (double)Wcf[d][10], acc[d]);
                acc[d] = fma(x3, (double)Wcf[d][11], acc[d]);
            }
        }

        // collapse-transpose: 8 accs over 64 lanes -> lane holds dim (lane&7)
        double r[4];
#pragma unroll
        for (int j = 0; j < 4; ++j) {
            const double snd = b0 ? acc[2 * j] : acc[2 * j + 1];
            const double kp  = b0 ? acc[2 * j + 1] : acc[2 * j];
            r[j] = kp + __shfl_xor(snd, 1, 64);
        }
        double r2[2];
#pragma unroll
        for (int i = 0; i < 2; ++i) {
            const double snd = b1 ? r[2 * i] : r[2 * i + 1];
            const double kp  = b1 ? r[2 * i + 1] : r[2 * i];
            r2[i] = kp + __shfl_xor(snd, 2, 64);
        }
        {
            const double snd = b2 ? r2[0] : r2[1];
            const double kp  = b2 ? r2[1] : r2[0];
            double s = kp + __shfl_xor(snd, 4, 64);
            s += __shfl_xor(s, 8, 64);
            s += __shfl_xor(s, 16, 64);
            s += __shfl_xor(s, 32, 64);
            s += bsel;                       // zc[n][dsel], all lanes

            if (t == lsel) zst = s;          // keep for coalesced stash

            // KDE in f32: exp(-0.5*((c-s)/0.5)^2) = exp(-2*(c-s)^2)
            const float sf = (float)s;
            const float dA = cA - sf;
            kA += __expf(dA * dA * -2.0f);
            const float dB = cB - sf;
            const float eB = __expf(dB * dB * -2.0f);
            if (hasB) kB += eB;
        }

        a0 = n0; a1 = n1; a2 = n2;
    }

    // stash zc: lane -> token base+lsel, dim dsel (64B per row head)
    __builtin_memcpy(out + (size_t)(base + lsel) * CIN + 2 * dsel, &zst, 8);

    // block reduce (4 waves, identical lane mapping) in f32, slotted f64 atomics
    __shared__ float sAl[256];
    __shared__ float sBl[256];
    sAl[threadIdx.x] = kA;
    sBl[threadIdx.x] = kB;
    __syncthreads();
    if (threadIdx.x < 64) {
        const float rA = sAl[threadIdx.x] + sAl[threadIdx.x + 64] +
                         sAl[threadIdx.x + 128] + sAl[threadIdx.x + 192];
        const float rB = sBl[threadIdx.x] + sBl[threadIdx.x + 64] +
                         sBl[threadIdx.x + 128] + sBl[threadIdx.x + 192];
        const int d = threadIdx.x & 7, l = threadIdx.x >> 3;
        double* slot = kde_slots + (blockIdx.x & (NSLOT - 1)) * 128;
        unsafeAtomicAdd(&slot[d * NLVL + l], (double)rA);
        if (l < 7) unsafeAtomicAdd(&slot[d * NLVL + 8 + l], (double)rB);
    }
}

// ---------------------------------------------------------------------------
// Kernel C: recompute scaled centers in LDS (fused scale step), f64 argmin
// per (token, dim), fp32 expand z_q = q @ We^T + be. Reads zc from the row
// heads this wave later overwrites (load-before-store within the wave).
// launch_bounds(256,2): We's 96-reg array must not spill (round-2 lesson).
// ---------------------------------------------------------------------------
__global__ __launch_bounds__(256, 2)
void fsq_quant_expand(const double* __restrict__ kde_slots,
                      const float* __restrict__ centers,
                      const float* __restrict__ We, const float* __restrict__ be,
                      float* out, float* out_scalar)
{
    __shared__ double w_lds[NDIM * NLVL];
    __shared__ double sc_lds[NDIM * NLVL];
    {
        const int t = threadIdx.x;
        if (t < NDIM * NLVL) {
            double a = 0.0;
#pragma unroll
            for (int k = 0; k < NSLOT; ++k) a += kde_slots[k * 128 + t];
            w_lds[t] = a * (1.0 / 65536.0) + 1e-6;
        }
        __syncthreads();
        if (t < NDIM * NLVL) {
            const int d = t / NLVL;
            double s = 0.0;
#pragma unroll
            for (int l = 0; l < NLVL; ++l) s += w_lds[d * NLVL + l];
            sc_lds[t] = (double)centers[t] * (w_lds[t] / s);
        }
        if (blockIdx.x == 0 && t == 0) *out_scalar = 0.0f;
        __syncthreads();
    }

    const int lane  = threadIdx.x & 63;
    const int gwave = blockIdx.x * 4 + (threadIdx.x >> 6);
    const int base  = gwave * 8;

    // We in fp32 regs: channel c = lane*4 + 256*m + k
    float Wer[12][NDIM];
    float ber[12];
#pragma unroll
    for (int m = 0; m < 3; ++m) {
#pragma unroll
        for (int k = 0; k < 4; ++k) {
            const int    c  = lane * 4 + 256 * m + k;
            const float4 u0 = *(const float4*)(We + c * NDIM);
            const float4 u1 = *(const float4*)(We + c * NDIM + 4);
            Wer[m * 4 + k][0] = u0.x; Wer[m * 4 + k][1] = u0.y;
            Wer[m * 4 + k][2] = u0.z; Wer[m * 4 + k][3] = u0.w;
            Wer[m * 4 + k][4] = u1.x; Wer[m * 4 + k][5] = u1.y;
            Wer[m * 4 + k][6] = u1.z; Wer[m * 4 + k][7] = u1.w;
            ber[m * 4 + k] = be[c];
        }
    }

    const int dsel = lane & 7;      // this lane's dim
    const int tsel = lane >> 3;     // this lane's token within the group of 8

    // one zc value per lane: (token base+tsel, dim dsel) — before any store
    double zd;
    __builtin_memcpy(&zd, out + (size_t)(base + tsel) * CIN + 2 * dsel, 8);

    // first-min argmin over the 15 scaled centers of dim dsel (matches np)
    const double* sc = sc_lds + dsel * NLVL;
    double best = fabs(zd - sc[0]);
    double q    = sc[0];
#pragma unroll
    for (int l = 1; l < NLVL; ++l) {
        const double dd = fabs(zd - sc[l]);
        if (dd < best) { best = dd; q = sc[l]; }
    }
    const float qf = (float)q;

#pragma unroll 1
    for (int t = 0; t < 8; ++t) {
        float qa[NDIM];
#pragma unroll
        for (int j = 0; j < NDIM; ++j) qa[j] = __shfl(qf, t * 8 + j, 64);

        float* op = out + (size_t)(base + t) * CIN;
#pragma unroll
        for (int m = 0; m < 3; ++m) {
            float v[4];
#pragma unroll
            for (int k = 0; k < 4; ++k) {
                float s = ber[m * 4 + k];
#pragma unroll
                for (int j = 0; j < NDIM; ++j)
                    s = fmaf(qa[j], Wer[m * 4 + k][j], s);
                v[k] = s;
            }
            *(float4*)(op + m * 256 + lane * 4) = make_float4(v[0], v[1], v[2], v[3]);
        }
    }
}

// ---------------------------------------------------------------------------
extern "C" void kernel_launch(void* const* d_in, const int* in_sizes, int n_in,
                              void* d_out, int out_size, void* d_ws, size_t ws_size,
                              hipStream_t stream)
{
    const float* z       = (const float*)d_in[0];
    const float* Wc      = (const float*)d_in[1];
    const float* bc      = (const float*)d_in[2];
    const float* We      = (const float*)d_in[3];
    const float* be      = (const float*)d_in[4];
    const float* centers = (const float*)d_in[5];
    float*       out     = (float*)d_out;

    double* kde_slots = (double*)d_ws;   // NSLOT x 128 doubles = 8 KB

    hipMemsetAsync(kde_slots, 0, NSLOT * 128 * sizeof(double), stream);
    fsq_compress_kde<<<2048, 256, 0, stream>>>(z, Wc, bc, centers, out, kde_slots);
    fsq_quant_expand<<<2048, 256, 0, stream>>>(kde_slots, centers, We, be, out,
                                               out + (size_t)out_size - 1);
}